// Round 11
// baseline (173.858 us; speedup 1.0000x reference)
//
#include <hip/hip_runtime.h>
#include <math.h>

// Problem constants (from reference)
#define DIMC   96
#define NHEADS 6
#define HD     16
#define WSZ    8
#define OWSZ   12
#define PADW   2
#define DD     24
#define LTOK   13824      // 24^3
#define NWIN   27         // 3^3
#define NKEY   1728       // 12^3
#define NROW   512        // 8^3
#define MLPH   192
#define PDIM   28         // 24 + 2*2
#define PD3    21952      // 28^3
#define TBL    6859       // 19^3
#define LSTR   82944      // 13824*6 (lbuf per-half stride)
#define AOSTR  1327104    // 13824*96 (ao per-half stride)
#define LOG2E  1.4426950408889634f

typedef __attribute__((ext_vector_type(4))) short bf16x4;
typedef __attribute__((ext_vector_type(8))) short bf16x8;
typedef __attribute__((ext_vector_type(4))) float f32x4;

// ---------------- helpers ----------------------------------------------------
__device__ __forceinline__ unsigned short bfround(float f) {
    unsigned u = __float_as_uint(f);
    return (unsigned short)((u + 0x7FFFu + ((u >> 16) & 1u)) >> 16);
}
__device__ __forceinline__ unsigned bfpack(float a, float b) {
    unsigned ua = __float_as_uint(a), ub = __float_as_uint(b);
    ua = (ua + 0x7FFFu + ((ua >> 16) & 1u)) >> 16;
    ub = (ub + 0x7FFFu + ((ub >> 16) & 1u)) >> 16;
    return ua | (ub << 16);
}
__device__ __forceinline__ uint4 pack8(const float* v) {
    uint4 u;
    u.x = bfpack(v[0], v[1]); u.y = bfpack(v[2], v[3]);
    u.z = bfpack(v[4], v[5]); u.w = bfpack(v[6], v[7]);
    return u;
}
// fp32x4 -> bf16x4 by truncation (P values; <0.4% rel bias; l uses same P)
__device__ __forceinline__ bf16x4 pack4(f32x4 p) {
    union { uint2 u; bf16x4 v; } r;
    r.u.x = __builtin_amdgcn_perm(__float_as_uint(p[1]), __float_as_uint(p[0]), 0x07060302u);
    r.u.y = __builtin_amdgcn_perm(__float_as_uint(p[3]), __float_as_uint(p[2]), 0x07060302u);
    return r.v;
}
__device__ __forceinline__ f32x4 mfma16(bf16x4 a, bf16x4 b, f32x4 c) {
#if __has_builtin(__builtin_amdgcn_mfma_f32_16x16x16bf16_1k)
    return __builtin_amdgcn_mfma_f32_16x16x16bf16_1k(a, b, c, 0, 0, 0);
#else
    bf16x8 a8 = {a[0], a[1], a[2], a[3], 0, 0, 0, 0};
    bf16x8 b8 = {b[0], b[1], b[2], b[3], 0, 0, 0, 0};
    return __builtin_amdgcn_mfma_f32_16x16x32_bf16(a8, b8, c, 0, 0, 0);
#endif
}
__device__ __forceinline__ f32x4 mfma32k(bf16x8 a, bf16x8 b, f32x4 c) {
    return __builtin_amdgcn_mfma_f32_16x16x32_bf16(a, b, c, 0, 0, 0);
}
__device__ __forceinline__ float fexp2(float x) {
#if __has_builtin(__builtin_amdgcn_exp2f)
    return __builtin_amdgcn_exp2f(x);
#else
    return exp2f(x);
#endif
}
__device__ __forceinline__ float frcp(float x) {
#if __has_builtin(__builtin_amdgcn_rcpf)
    return __builtin_amdgcn_rcpf(x);
#else
    return 1.0f / x;
#endif
}
// exp2-based tanh GELU: abs err ~1e-5 at this operand scale (<< bf16 rounding)
__device__ __forceinline__ float fgelu(float v) {
    float v2 = v * v;
    float t  = v * fmaf(0.10294456f, v2, 2.3022585f);  // 2u*log2(e)
    float e  = fexp2(t);
    return v - v * frcp(e + 1.0f);                     // v*(1 - 1/(e^{2u}+1))
}

// ---------------- kernel 1: qkv GEMM + border zero + weight pack + bias pack -
// Sequential block ranges:
//   [0, 432)             qkv GEMM block: ALL 3 nc per block (LN1+A-stage once)
//   [432, 947)           zero PAD BORDER of kvp2 (disjoint from qkv writes)
//   [947, 992)           pack proj/fc1/fc2 weights -> wpack bf16 frag-linear
//   [992, 1208)          bias pack: F32, FULLY COALESCED layout
//                        [head*4+quart][c][qt 2][kt 4][tid 256][r 4] f32
#define QKVB 432
#define ZB   515     // ceil(21952*6/256)
#define WPB  45      // 5760 uint4 / 256 (rounded up)
#define BIASB 216    // 27 c x 4 quart x 2 qt
__global__ __launch_bounds__(256) void qkvz_kernel(
        const float* __restrict__ X, const float* __restrict__ W,
        const float* __restrict__ bias, const float* __restrict__ lnw,
        const float* __restrict__ lnb,
        const float* __restrict__ projw, const float* __restrict__ fc1w,
        const float* __restrict__ fc2w,
        const int* __restrict__ rpi, const float* __restrict__ rpb,
        unsigned short* __restrict__ q16, unsigned short* __restrict__ kvp2,
        uint4* __restrict__ wpack, float* __restrict__ biasF) {
    __shared__ uint4 Af4[2 * 3 * 4 * 16];   // 6 KB
    __shared__ uint4 Bf4[3 * 1152];         // 54 KB (all 3 nc)
    int bx = blockIdx.x, tid = threadIdx.x;

    if (bx >= QKVB + ZB + WPB) {   // ---- bias pack (f32, coalesced) ----
        int b2 = bx - (QKVB + ZB + WPB);   // 0..215
        int c  = b2 % 27;
        int qp = b2 / 27;                  // 0..7
        int quart = qp >> 1, qt = qp & 1;
        int quadp = (tid >> 4) & 3, m16p = tid & 15;
        int wavep = tid >> 6;
        int q = quart * 128 + wavep * 32 + qt * 16 + m16p;
        const int* rp = rpi + (long)q * NKEY + c * 64 + quadp * 8;
        #pragma unroll
        for (int kt = 0; kt < 4; ++kt) {
            // physical keys for S tile kt, quad quadp, r=0..3:
            //   c*64 + (kt>>1)*32 + (kt&1)*4 + quadp*8 + r
            int4 t = *(const int4*)(rp + (kt >> 1) * 32 + (kt & 1) * 4);
            const float* b0 = rpb + (long)t.x * 6;
            const float* b1 = rpb + (long)t.y * 6;
            const float* b2p = rpb + (long)t.z * 6;
            const float* b3 = rpb + (long)t.w * 6;
            float4 q0 = *(const float4*)b0; float2 r0 = *(const float2*)(b0 + 4);
            float4 q1 = *(const float4*)b1; float2 r1 = *(const float2*)(b1 + 4);
            float4 q2 = *(const float4*)b2p; float2 r2 = *(const float2*)(b2p + 4);
            float4 q3 = *(const float4*)b3; float2 r3 = *(const float2*)(b3 + 4);
            float4 h[6];
            h[0] = make_float4(q0.x * LOG2E, q1.x * LOG2E, q2.x * LOG2E, q3.x * LOG2E);
            h[1] = make_float4(q0.y * LOG2E, q1.y * LOG2E, q2.y * LOG2E, q3.y * LOG2E);
            h[2] = make_float4(q0.z * LOG2E, q1.z * LOG2E, q2.z * LOG2E, q3.z * LOG2E);
            h[3] = make_float4(q0.w * LOG2E, q1.w * LOG2E, q2.w * LOG2E, q3.w * LOG2E);
            h[4] = make_float4(r0.x * LOG2E, r1.x * LOG2E, r2.x * LOG2E, r3.x * LOG2E);
            h[5] = make_float4(r0.y * LOG2E, r1.y * LOG2E, r2.y * LOG2E, r3.y * LOG2E);
            #pragma unroll
            for (int head = 0; head < 6; ++head) {
                float* o = biasF + ((long)(head * 4 + quart) * 27 + c) * 8192
                           + (qt * 4 + kt) * 1024 + tid * 4;
                *(float4*)o = h[head];
            }
        }
        return;
    }
    if (bx >= QKVB + ZB) {   // ---- weight pack ----
        int u = (bx - QKVB - ZB) * 256 + tid;
        if (u < 5760) {
            int p = (u < 1152) ? u : (u < 3456 ? (u - 1152) % 1152 : (u - 3456) % 1152);
            int nn = p & 15, r = p >> 4, qg = r & 3, r2 = r >> 2;
            int kt = r2 % 3, ct = r2 / 3;
            int n = ct * 16 + nn, g = kt * 4 + qg;
            const float* src;
            if (u < 1152)      src = projw + n * 96 + g * 8;
            else if (u < 3456) { int nc = (u - 1152) / 1152; src = fc1w + (long)(nc * 96 + n) * 96 + g * 8; }
            else               { int kh = (u - 3456) / 1152; src = fc2w + (long)n * 192 + kh * 96 + g * 8; }
            const float4* s4 = (const float4*)src;
            float v[8];
            float4 t0 = s4[0], t1 = s4[1];
            v[0]=t0.x; v[1]=t0.y; v[2]=t0.z; v[3]=t0.w;
            v[4]=t1.x; v[5]=t1.y; v[6]=t1.z; v[7]=t1.w;
            wpack[u] = pack8(v);
        }
        return;
    }
    if (bx >= QKVB) {        // ---- pad-border zero ----
        int t = (bx - QKVB) * 256 + tid;
        if (t < 21952 * 6) {
            int head = t / PD3, pos = t % PD3;
            int d = pos / 784, h = (pos / 28) % 28, w = pos % 28;
            if (d < 2 || d >= 26 || h < 2 || h >= 26 || w < 2 || w >= 26) {
                uint4* p = (uint4*)(kvp2 + ((long)head * PD3 + pos) * 32);
                uint4 z = make_uint4(0, 0, 0, 0);
                p[0] = z; p[1] = z; p[2] = z; p[3] = z;
            }
        }
        return;
    }

    // ---- qkv GEMM block: 32 rows x all 288 output cols ----
    int row0 = bx * 32;

    if (tid < 128) {   // stage A with LN1: 32 rows, 4 threads/row (ONCE)
        int row = tid >> 2, part = tid & 3;
        int rt = row >> 4, mm = row & 15;
        float v[24];
        const float4* xp = (const float4*)(X + (long)(row0 + row) * 96 + part * 24);
        float s = 0.f, sq = 0.f;
        #pragma unroll
        for (int i = 0; i < 6; ++i) {
            float4 t = xp[i];
            v[i*4+0] = t.x; v[i*4+1] = t.y; v[i*4+2] = t.z; v[i*4+3] = t.w;
            s  += t.x + t.y + t.z + t.w;
            sq += t.x*t.x + t.y*t.y + t.z*t.z + t.w*t.w;
        }
        s  += __shfl_xor(s, 1);  s  += __shfl_xor(s, 2);
        sq += __shfl_xor(sq, 1); sq += __shfl_xor(sq, 2);
        float mean = s * (1.f / 96.f);
        float inv  = rsqrtf(sq * (1.f / 96.f) - mean * mean + 1e-5f);
        const float4* wp = (const float4*)(lnw + part * 24);
        const float4* bp = (const float4*)(lnb + part * 24);
        #pragma unroll
        for (int i = 0; i < 6; ++i) {
            float4 wv = wp[i], bv = bp[i];
            v[i*4+0] = (v[i*4+0] - mean) * inv * wv.x + bv.x;
            v[i*4+1] = (v[i*4+1] - mean) * inv * wv.y + bv.y;
            v[i*4+2] = (v[i*4+2] - mean) * inv * wv.z + bv.z;
            v[i*4+3] = (v[i*4+3] - mean) * inv * wv.w + bv.w;
        }
        #pragma unroll
        for (int gg = 0; gg < 3; ++gg) {
            int g = part * 3 + gg;
            int kt = g >> 2, qq = g & 3;
            Af4[((rt * 3 + kt) * 4 + qq) * 16 + mm] = pack8(v + gg * 8);
        }
    }
    for (int idx = tid; idx < 3 * 1152; idx += 256) {   // stage B: all 3 nc
        int nc = idx / 1152, p = idx % 1152;
        int n = p / 12;
        int g = p % 12;
        const float4* wp = (const float4*)(W + (long)(nc * 96 + n) * 96 + g * 8);
        float v[8];
        float4 t0 = wp[0], t1 = wp[1];
        v[0]=t0.x; v[1]=t0.y; v[2]=t0.z; v[3]=t0.w;
        v[4]=t1.x; v[5]=t1.y; v[6]=t1.z; v[7]=t1.w;
        int ct = n >> 4, nn = n & 15, kt = g >> 2, qg = g & 3;
        Bf4[nc * 1152 + ((ct * 3 + kt) * 4 + qg) * 16 + nn] = pack8(v);
    }
    __syncthreads();

    int wave = tid >> 6, lane = tid & 63;
    int qq = lane >> 4, mI = lane & 15;
    int rt = wave & 1, cg = wave >> 1;

    bf16x8 a[3];
    #pragma unroll
    for (int kt = 0; kt < 3; ++kt)
        a[kt] = *(const bf16x8*)&Af4[((rt * 3 + kt) * 4 + qq) * 16 + mI];

    #pragma unroll
    for (int nc = 0; nc < 3; ++nc) {
        f32x4 acc[3];
        #pragma unroll
        for (int j = 0; j < 3; ++j) acc[j] = (f32x4){0.f, 0.f, 0.f, 0.f};
        #pragma unroll
        for (int kt = 0; kt < 3; ++kt) {
            #pragma unroll
            for (int j = 0; j < 3; ++j) {
                bf16x8 b = *(const bf16x8*)&Bf4[nc * 1152 +
                               (((cg * 3 + j) * 3 + kt) * 4 + qq) * 16 + mI];
                acc[j] = __builtin_amdgcn_mfma_f32_16x16x32_bf16(a[kt], b, acc[j], 0, 0, 0);
            }
        }
        float bv[3];
        #pragma unroll
        for (int j = 0; j < 3; ++j) bv[j] = bias[nc * 96 + (cg * 3 + j) * 16 + mI];
        #pragma unroll
        for (int r = 0; r < 4; ++r) {
            int row = row0 + rt * 16 + qq * 4 + r;
            if (nc == 0) {
                unsigned short* op = q16 + (long)row * 96;
                // 0.25 (hd^-0.5) * log2(e): enables raw v_exp (2^x) in attention
                #pragma unroll
                for (int j = 0; j < 3; ++j)
                    op[(cg * 3 + j) * 16 + mI] = bfround(0.25f * LOG2E * (acc[j][r] + bv[j]));
            } else {
                int d = row / 576, hh = (row / 24) % 24, w2 = row % 24;
                long pos = ((long)(d + 2) * 28 + (hh + 2)) * 28 + (w2 + 2);
                #pragma unroll
                for (int j = 0; j < 3; ++j) {
                    int head = cg * 3 + j;
                    kvp2[((long)head * PD3 + pos) * 32 +
                         (nc == 2 ? 16 : 0) + mI] = bfround(acc[j][r] + bv[j]);
                }
            }
        }
    }
}

// ---------------- kernel 2: MFMA flash attention -----------------------------
// O = P·V formulation, zero shuffles. VKP=72 keeps the Vt ds_read_b128
// conflict-free (R10: conflicts 1.12M -> 560K confirmed the read fix), and
// the part3 write-slot rotation keeps writes <=2-way -- but R10 implemented
// the rotation with a RUNTIME-indexed local array (s[(i+rot)&7], rot per-lane)
// which went to SCRATCH (rule #20: VGPR 72->80, +20us). This revision keeps
// identical semantics with COMPILE-TIME indices only: per unrolled i, both
// candidate slots (i and (i+4)&7) are literals; a ternary on part selects
// value and dim via v_cndmask. f32 bias (R8) kept.
#define KSTR 20
#define VKP  72   // transposed-V row stride (shorts): b128 reads 2-way uniform

#define ATTN_STEP(P, BB)                                                      \
    {                                                                         \
        bool morekv = (cc + (P) + 1 < cn);                                    \
        if (morekv) stgn = *kvaddr(c0 + cc + (P) + 1);                        \
        __syncthreads();                                                      \
        bf16x4 kf[4];                                                         \
        _Pragma("unroll")                                                     \
        for (int kt = 0; kt < 4; ++kt)                                        \
            kf[kt] = *(const bf16x4*)&Ks[(P)][(kt * 16 + m16) * KSTR + quad * 4]; \
        bf16x8 vb0 = *(const bf16x8*)&Vt[(P)][m16 * VKP + quad * 8];          \
        bf16x8 vb1 = *(const bf16x8*)&Vt[(P)][m16 * VKP + 32 + quad * 8];     \
        f32x4 S[2][4];                                                        \
        _Pragma("unroll")                                                     \
        for (int qt = 0; qt < 2; ++qt) {                                      \
            _Pragma("unroll")                                                 \
            for (int kt = 0; kt < 4; ++kt)                                    \
                S[qt][kt] = mfma16(kf[kt], qf[qt], BB[qt][kt]);               \
        }                                                                     \
        if (cc + (P) + 2 < cn) {                                              \
            const float* bp = bbase + (long)(c0 + cc + (P) + 2) * 8192        \
                              + tid * 4;                                      \
            _Pragma("unroll")                                                 \
            for (int qt = 0; qt < 2; ++qt) {                                  \
                _Pragma("unroll")                                             \
                for (int kt = 0; kt < 4; ++kt)                                \
                    BB[qt][kt] = *(const f32x4*)(bp + (qt * 4 + kt) * 1024);  \
            }                                                                 \
        }                                                                     \
        bf16x8 P8[2][2];                                                      \
        _Pragma("unroll")                                                     \
        for (int qt = 0; qt < 2; ++qt) {                                      \
            _Pragma("unroll")                                                 \
            for (int u = 0; u < 2; ++u) {                                     \
                f32x4 p0, p1;                                                 \
                _Pragma("unroll")                                             \
                for (int r = 0; r < 4; ++r) {                                 \
                    p0[r] = fexp2(S[qt][2 * u][r]);                           \
                    p1[r] = fexp2(S[qt][2 * u + 1][r]);                       \
                }                                                             \
                union { struct { bf16x4 lo, hi; } h; bf16x8 v; } uu;          \
                uu.h.lo = pack4(p0); uu.h.hi = pack4(p1);                     \
                P8[qt][u] = uu.v;                                             \
                lacc[qt] = mfma32k(P8[qt][u], ones8, lacc[qt]);               \
            }                                                                 \
        }                                                                     \
        o[0] = mfma32k(P8[0][0], vb0, o[0]);                                  \
        o[1] = mfma32k(P8[1][0], vb0, o[1]);                                  \
        o[0] = mfma32k(P8[0][1], vb1, o[0]);                                  \
        o[1] = mfma32k(P8[1][1], vb1, o[1]);                                  \
        if (morekv) writeLDS((P) ^ 1, stgn);                                  \
    }

__global__ __launch_bounds__(256, 3) void attn_kernel(
        const unsigned short* __restrict__ q, const unsigned short* __restrict__ kvp2,
        const float* __restrict__ biasF, float* __restrict__ ao,
        float* __restrict__ lbuf) {
    __shared__ unsigned short Ks[2][64 * KSTR];   // 5120 B, sigma-permuted
    __shared__ unsigned short Vt[2][16 * VKP];    // 4608 B, transposed [dim][key]
    int bid = blockIdx.x;                 // 27*6*4*2 = 1296
    int w = bid / 48, rem = bid % 48;
    int head = rem >> 3;
    int quart = (rem >> 1) & 3, half = rem & 1;
    int wd8 = (w / 9) * 8, wh8 = ((w / 3) % 3) * 8, ww8 = (w % 3) * 8;
    int tid = threadIdx.x, wave = tid >> 6, lane = tid & 63;
    int quad = lane >> 4, m16 = lane & 15;
    int key = tid >> 2, part = tid & 3;
    int c0 = half ? 13 : 0;
    int cn = half ? 14 : 13;

    // sigma: key k = 32u+8b+4c+r  ->  LDS row 32u+16c+4b+r.  Makes the
    // interleaved kf read land on rows kt*16+m16 (linear, conflict-free).
    int skey = (key & 35) | ((key & 4) << 2) | ((key >> 1) & 12);

    auto kvaddr = [&](int c) -> const uint4* {
        int jg = c * 64 + key;
        int i = jg / 144, jh = (jg / 12) % 12, jw = jg % 12;
        long sp = ((long)(wd8 + i) * PDIM + (wh8 + jh)) * PDIM + (ww8 + jw);
        return (const uint4*)(kvp2 + ((long)head * PD3 + sp) * 32 + part * 8);
    };
    auto writeLDS = [&](int b, uint4 v) {
        if (part < 2) {
            *(uint2*)(&Ks[b][skey * KSTR + part * 8])     = make_uint2(v.x, v.y);
            *(uint2*)(&Ks[b][skey * KSTR + part * 8 + 4]) = make_uint2(v.z, v.w);
        } else {
            int d0 = (part - 2) * 8;
            bool p3 = (part & 1);
            unsigned short e[8];   // constant-indexed only -> stays in VGPRs
            e[0] = (unsigned short)(v.x); e[1] = (unsigned short)(v.x >> 16);
            e[2] = (unsigned short)(v.y); e[3] = (unsigned short)(v.y >> 16);
            e[4] = (unsigned short)(v.z); e[5] = (unsigned short)(v.z >> 16);
            e[6] = (unsigned short)(v.w); e[7] = (unsigned short)(v.w >> 16);
            #pragma unroll
            for (int i = 0; i < 8; ++i) {
                const int i2 = (i + 4) & 7;          // literal per iteration
                int j = p3 ? i2 : i;                  // cndmask, not indexing
                unsigned short val = p3 ? e[i2] : e[i];
                Vt[b][(d0 + j) * VKP + key] = val;
            }
        }
    };

    bf16x4 qf[2];
    #pragma unroll
    for (int qt = 0; qt < 2; ++qt) {
        int ql = quart * 128 + wave * 32 + qt * 16 + m16;
        int ld = ql >> 6, lh = (ql >> 3) & 7, lw = ql & 7;
        int g = ((wd8 + ld) * 24 + (wh8 + lh)) * 24 + (ww8 + lw);
        qf[qt] = *(const bf16x4*)(q + (long)g * 96 + head * 16 + quad * 4);
    }

    // bias: [head*4+quart][c][qt][kt][tid][r] f32 -- coalesced float4 loads
    const float* bbase = biasF + ((long)(head * 4 + quart) * 27) * 8192;
    f32x4 bb0[2][4], bb1[2][4];
    {
        const float* bp = bbase + (long)c0 * 8192 + tid * 4;
        #pragma unroll
        for (int qt = 0; qt < 2; ++qt)
            #pragma unroll
            for (int kt = 0; kt < 4; ++kt)
                bb0[qt][kt] = *(const f32x4*)(bp + (qt * 4 + kt) * 1024);
        const float* bp1 = bbase + (long)(c0 + 1) * 8192 + tid * 4;
        #pragma unroll
        for (int qt = 0; qt < 2; ++qt)
            #pragma unroll
            for (int kt = 0; kt < 4; ++kt)
                bb1[qt][kt] = *(const f32x4*)(bp1 + (qt * 4 + kt) * 1024);
    }

    writeLDS(0, *kvaddr(c0));

    const bf16x8 ones8 = {(short)0x3F80, (short)0x3F80, (short)0x3F80, (short)0x3F80,
                          (short)0x3F80, (short)0x3F80, (short)0x3F80, (short)0x3F80};
    f32x4 o[2], lacc[2];
    o[0] = (f32x4){0.f,0.f,0.f,0.f}; o[1] = (f32x4){0.f,0.f,0.f,0.f};
    lacc[0] = o[0]; lacc[1] = o[1];
    uint4 stgn;

    for (int cc = 0; cc < cn; cc += 2) {
        ATTN_STEP(0, bb0)
        if (cc + 1 < cn) ATTN_STEP(1, bb1)
    }

    // epilogue: O in C layout [q=quad*4+r][dim=m16]
    float* aout = ao + (long)half * AOSTR;
    float* lout = lbuf + (long)half * LSTR;
    #pragma unroll
    for (int qt = 0; qt < 2; ++qt) {
        #pragma unroll
        for (int r = 0; r < 4; ++r) {
            int ql = quart * 128 + wave * 32 + qt * 16 + quad * 4 + r;
            int ld = ql >> 6, lh = (ql >> 3) & 7, lw = ql & 7;
            int g = ((wd8 + ld) * 24 + (wh8 + lh)) * 24 + (ww8 + lw);
            aout[(long)g * 96 + head * 16 + m16] = o[qt][r];
            if (m16 == 0) lout[g * 6 + head] = lacc[qt][r];
        }
    }
}

// ---------------- kernel 3: fused MLP, 512 thr x 64 rows, weights resident ---
// GELU via exp2-tanh form (7 VALU + 1 trans vs ~25 for erff; abs err ~1e-5,
// far below the bf16-quantization-dominated absmax).
#define X2S 100
__global__ __launch_bounds__(512) void mlp_kernel(
        const float* __restrict__ ao0, const float* __restrict__ ao1,
        const float* __restrict__ lbuf, const uint4* __restrict__ wpack,
        const float* __restrict__ projb, const float* __restrict__ x,
        const float* __restrict__ ln2w, const float* __restrict__ ln2b,
        const float* __restrict__ fc1b, const float* __restrict__ fc2b,
        float* __restrict__ out) {
    __shared__ uint4 Ws[5760];               // 92160 B: proj | fc1(2) | fc2(2)
    __shared__ uint4 Af4[4 * 3 * 4 * 16];    // 12288 B
    __shared__ float x2s[64 * X2S];          // 25600 B
    __shared__ unsigned short h16[64 * 192]; // 24576 B  => 154624 B total
    int tid = threadIdx.x;
    int row0 = blockIdx.x * 64;
    int wave = tid >> 6, lane = tid & 63;
    int qq = lane >> 4, mI = lane & 15;
    int rt = wave & 3, cg = wave >> 2;       // 4 row tiles x 2 col groups

    for (int idx = tid; idx < 5760; idx += 512) Ws[idx] = wpack[idx];

    if (tid < 256) {
        int row = tid >> 2, part = tid & 3;
        int rtA = row >> 4, mm = row & 15;
        int grow = row0 + row;
        const float4* a0 = (const float4*)(ao0 + (long)grow * 96 + part * 24);
        const float4* a1 = (const float4*)(ao1 + (long)grow * 96 + part * 24);
        int ha = (part * 3) >> 1, hb = ha + 1;
        float inva = 1.f / (lbuf[grow*6 + ha] + lbuf[LSTR + grow*6 + ha]);
        float invb = 1.f / (lbuf[grow*6 + hb] + lbuf[LSTR + grow*6 + hb]);
        float v[24];
        #pragma unroll
        for (int i = 0; i < 6; ++i) {
            float4 u0 = a0[i], u1 = a1[i];
            #pragma unroll
            for (int j = 0; j < 4; ++j) {
                int gc = part * 24 + i * 4 + j;
                float lv = ((gc >> 4) == ha) ? inva : invb;
                float s = (j==0?u0.x+u1.x : j==1?u0.y+u1.y : j==2?u0.z+u1.z : u0.w+u1.w);
                v[i*4+j] = s * lv;
            }
        }
        #pragma unroll
        for (int gg = 0; gg < 3; ++gg) {
            int g = part * 3 + gg;
            int kt = g >> 2, q4 = g & 3;
            Af4[((rtA * 3 + kt) * 4 + q4) * 16 + mm] = pack8(v + gg * 8);
        }
    }
    __syncthreads();

    {
        f32x4 acc[3];
        #pragma unroll
        for (int j = 0; j < 3; ++j) acc[j] = (f32x4){0.f,0.f,0.f,0.f};
        #pragma unroll
        for (int kt = 0; kt < 3; ++kt) {
            bf16x8 a = *(const bf16x8*)&Af4[((rt * 3 + kt) * 4 + qq) * 16 + mI];
            #pragma unroll
            for (int j = 0; j < 3; ++j) {
                bf16x8 b = *(const bf16x8*)&Ws[(((cg * 3 + j) * 3 + kt) * 4 + qq) * 16 + mI];
                acc[j] = __builtin_amdgcn_mfma_f32_16x16x32_bf16(a, b, acc[j], 0, 0, 0);
            }
        }
        float bv[3];
        #pragma unroll
        for (int j = 0; j < 3; ++j) bv[j] = projb[(cg * 3 + j) * 16 + mI];
        #pragma unroll
        for (int r = 0; r < 4; ++r) {
            int row = rt * 16 + qq * 4 + r;
            int grow = row0 + row;
            #pragma unroll
            for (int j = 0; j < 3; ++j) {
                int col = (cg * 3 + j) * 16 + mI;
                x2s[row * X2S + col] = acc[j][r] + bv[j] + x[(long)grow * 96 + col];
            }
        }
    }
    __syncthreads();

    if (tid < 256) {
        int row = tid >> 2, part = tid & 3;
        int rtA = row >> 4, mm = row & 15;
        float v[24];
        const float4* xp = (const float4*)(x2s + row * X2S + part * 24);
        float s = 0.f, sq = 0.f;
        #pragma unroll
        for (int i = 0; i < 6; ++i) {
            float4 t = xp[i];
            v[i*4+0] = t.x; v[i*4+1] = t.y; v[i*4+2] = t.z; v[i*4+3] = t.w;
            s  += t.x + t.y + t.z + t.w;
            sq += t.x*t.x + t.y*t.y + t.z*t.z + t.w*t.w;
        }
        s  += __shfl_xor(s, 1);  s  += __shfl_xor(s, 2);
        sq += __shfl_xor(sq, 1); sq += __shfl_xor(sq, 2);
        float mean = s * (1.f / 96.f);
        float inv  = rsqrtf(sq * (1.f / 96.f) - mean * mean + 1e-5f);
        const float4* wp = (const float4*)(ln2w + part * 24);
        const float4* bp = (const float4*)(ln2b + part * 24);
        #pragma unroll
        for (int i = 0; i < 6; ++i) {
            float4 wv = wp[i], bv = bp[i];
            v[i*4+0] = (v[i*4+0] - mean) * inv * wv.x + bv.x;
            v[i*4+1] = (v[i*4+1] - mean) * inv * wv.y + bv.y;
            v[i*4+2] = (v[i*4+2] - mean) * inv * wv.z + bv.z;
            v[i*4+3] = (v[i*4+3] - mean) * inv * wv.w + bv.w;
        }
        #pragma unroll
        for (int gg = 0; gg < 3; ++gg) {
            int g = part * 3 + gg;
            int kt = g >> 2, q4 = g & 3;
            Af4[((rtA * 3 + kt) * 4 + q4) * 16 + mm] = pack8(v + gg * 8);
        }
    }
    __syncthreads();

    #pragma unroll
    for (int nc = 0; nc < 2; ++nc) {
        f32x4 acc[3];
        #pragma unroll
        for (int j = 0; j < 3; ++j) acc[j] = (f32x4){0.f,0.f,0.f,0.f};
        #pragma unroll
        for (int kt = 0; kt < 3; ++kt) {
            bf16x8 a = *(const bf16x8*)&Af4[((rt * 3 + kt) * 4 + qq) * 16 + mI];
            #pragma unroll
            for (int j = 0; j < 3; ++j) {
                bf16x8 b = *(const bf16x8*)&Ws[1152 + nc * 1152 +
                               (((cg * 3 + j) * 3 + kt) * 4 + qq) * 16 + mI];
                acc[j] = __builtin_amdgcn_mfma_f32_16x16x32_bf16(a, b, acc[j], 0, 0, 0);
            }
        }
        float bv[3];
        #pragma unroll
        for (int j = 0; j < 3; ++j) bv[j] = fc1b[nc * 96 + (cg * 3 + j) * 16 + mI];
        #pragma unroll
        for (int r = 0; r < 4; ++r) {
            int row = rt * 16 + qq * 4 + r;
            #pragma unroll
            for (int j = 0; j < 3; ++j) {
                int col = nc * 96 + (cg * 3 + j) * 16 + mI;
                float v = acc[j][r] + bv[j];
                float g = fgelu(v);
                int fi = (((row >> 4) * 6 + (col >> 5)) * 4 + ((col >> 3) & 3)) * 16 + (row & 15);
                h16[fi * 8 + (col & 7)] = bfround(g);
            }
        }
    }
    __syncthreads();

    f32x4 acc2[3];
    #pragma unroll
    for (int j = 0; j < 3; ++j) acc2[j] = (f32x4){0.f,0.f,0.f,0.f};
    #pragma unroll
    for (int kh = 0; kh < 2; ++kh) {
        #pragma unroll
        for (int kt = 0; kt < 3; ++kt) {
            int ktA = kh * 3 + kt;
            bf16x8 a = *(const bf16x8*)&h16[(((rt * 6 + ktA) * 4 + qq) * 16 + mI) * 8];
            #pragma unroll
            for (int j = 0; j < 3; ++j) {
                bf16x8 b = *(const bf16x8*)&Ws[3456 + kh * 1152 +
                               (((cg * 3 + j) * 3 + kt) * 4 + qq) * 16 + mI];
                acc2[j] = __builtin_amdgcn_mfma_f32_16x16x32_bf16(a, b, acc2[j], 0, 0, 0);
            }
        }
    }
    float bv[3];
    #pragma unroll
    for (int j = 0; j < 3; ++j) bv[j] = fc2b[(cg * 3 + j) * 16 + mI];
    #pragma unroll
    for (int r = 0; r < 4; ++r) {
        int row = rt * 16 + qq * 4 + r;
        int grow = row0 + row;
        #pragma unroll
        for (int j = 0; j < 3; ++j) {
            int col = (cg * 3 + j) * 16 + mI;
            out[(long)grow * 96 + col] = acc2[j][r] + bv[j] + x2s[row * X2S + col];
        }
    }
}

// ---------------- launcher ---------------------------------------------------
extern "C" void kernel_launch(void* const* d_in, const int* in_sizes, int n_in,
                              void* d_out, int out_size, void* d_ws, size_t ws_size,
                              hipStream_t stream) {
    const float* x     = (const float*)d_in[0];
    const float* ln1w  = (const float*)d_in[1];
    const float* ln1b  = (const float*)d_in[2];
    const float* qkvw  = (const float*)d_in[3];
    const float* qkvb  = (const float*)d_in[4];
    const float* rpb   = (const float*)d_in[5];
    const float* projw = (const float*)d_in[6];
    const float* projb = (const float*)d_in[7];
    const float* ln2w  = (const float*)d_in[8];
    const float* ln2b  = (const float*)d_in[9];
    const float* fc1w  = (const float*)d_in[10];
    const float* fc1b  = (const float*)d_in[11];
    const float* fc2w  = (const float*)d_in[12];
    const float* fc2b  = (const float*)d_in[13];
    const int*   rpi   = (const int*)d_in[14];
    float* outp = (float*)d_out;

    float* ws = (float*)d_ws;
    float*          aop    = ws;                               // 2 x 1,327,104 f
    unsigned short* q16    = (unsigned short*)(ws + 2654208);  // 663,552 f
    unsigned short* kvp16  = (unsigned short*)(ws + 3317760);  // 2,107,392 f
    float*          biasF  = ws + 5425152;                     // 5,308,416 f (f32)
    float*          lbuf   = ws + 10733568;                    // 165,888 f
    uint4*          wpack  = (uint4*)(ws + 10899456);          // 23,040 f (5760 u4)

    qkvz_kernel<<<QKVB + ZB + WPB + BIASB, 256, 0, stream>>>(
        x, qkvw, qkvb, ln1w, ln1b, projw, fc1w, fc2w, rpi, rpb,
        q16, kvp16, wpack, biasF);
    attn_kernel<<<NWIN * NHEADS * 4 * 2, 256, 0, stream>>>(q16, kvp16, biasF, aop, lbuf);
    mlp_kernel<<<LTOK / 64, 512, 0, stream>>>(aop, aop + AOSTR, lbuf, wpack, projb, x,
                                              ln2w, ln2b, fc1b, fc2b, outp);
}

// Round 12
// 156.672 us; speedup vs baseline: 1.1097x; 1.1097x over previous
//
#include <hip/hip_runtime.h>
#include <math.h>

// Problem constants (from reference)
#define DIMC   96
#define NHEADS 6
#define HD     16
#define WSZ    8
#define OWSZ   12
#define PADW   2
#define DD     24
#define LTOK   13824      // 24^3
#define NWIN   27         // 3^3
#define NKEY   1728       // 12^3
#define NROW   512        // 8^3
#define MLPH   192
#define PDIM   28         // 24 + 2*2
#define PD3    21952      // 28^3
#define TBL    6859       // 19^3
#define LSTR   82944      // 13824*6 (lbuf per-half stride)
#define AOSTR  1327104    // 13824*96 (ao per-half stride)
#define LOG2E  1.4426950408889634f

typedef __attribute__((ext_vector_type(4))) short bf16x4;
typedef __attribute__((ext_vector_type(8))) short bf16x8;
typedef __attribute__((ext_vector_type(4))) float f32x4;

// ---------------- helpers ----------------------------------------------------
__device__ __forceinline__ unsigned short bfround(float f) {
    unsigned u = __float_as_uint(f);
    return (unsigned short)((u + 0x7FFFu + ((u >> 16) & 1u)) >> 16);
}
__device__ __forceinline__ unsigned bfpack(float a, float b) {
    unsigned ua = __float_as_uint(a), ub = __float_as_uint(b);
    ua = (ua + 0x7FFFu + ((ua >> 16) & 1u)) >> 16;
    ub = (ub + 0x7FFFu + ((ub >> 16) & 1u)) >> 16;
    return ua | (ub << 16);
}
__device__ __forceinline__ uint4 pack8(const float* v) {
    uint4 u;
    u.x = bfpack(v[0], v[1]); u.y = bfpack(v[2], v[3]);
    u.z = bfpack(v[4], v[5]); u.w = bfpack(v[6], v[7]);
    return u;
}
// fp32x4 -> bf16x4 by truncation (P values; <0.4% rel bias; l uses same P)
__device__ __forceinline__ bf16x4 pack4(f32x4 p) {
    union { uint2 u; bf16x4 v; } r;
    r.u.x = __builtin_amdgcn_perm(__float_as_uint(p[1]), __float_as_uint(p[0]), 0x07060302u);
    r.u.y = __builtin_amdgcn_perm(__float_as_uint(p[3]), __float_as_uint(p[2]), 0x07060302u);
    return r.v;
}
__device__ __forceinline__ f32x4 mfma16(bf16x4 a, bf16x4 b, f32x4 c) {
#if __has_builtin(__builtin_amdgcn_mfma_f32_16x16x16bf16_1k)
    return __builtin_amdgcn_mfma_f32_16x16x16bf16_1k(a, b, c, 0, 0, 0);
#else
    bf16x8 a8 = {a[0], a[1], a[2], a[3], 0, 0, 0, 0};
    bf16x8 b8 = {b[0], b[1], b[2], b[3], 0, 0, 0, 0};
    return __builtin_amdgcn_mfma_f32_16x16x32_bf16(a8, b8, c, 0, 0, 0);
#endif
}
__device__ __forceinline__ f32x4 mfma32k(bf16x8 a, bf16x8 b, f32x4 c) {
    return __builtin_amdgcn_mfma_f32_16x16x32_bf16(a, b, c, 0, 0, 0);
}
__device__ __forceinline__ float fexp2(float x) {
#if __has_builtin(__builtin_amdgcn_exp2f)
    return __builtin_amdgcn_exp2f(x);
#else
    return exp2f(x);
#endif
}
__device__ __forceinline__ float frcp(float x) {
#if __has_builtin(__builtin_amdgcn_rcpf)
    return __builtin_amdgcn_rcpf(x);
#else
    return 1.0f / x;
#endif
}
// exp2-based tanh GELU: abs err ~1e-5 at this operand scale (<< bf16 rounding)
__device__ __forceinline__ float fgelu(float v) {
    float v2 = v * v;
    float t  = v * fmaf(0.10294456f, v2, 2.3022585f);  // 2u*log2(e)
    float e  = fexp2(t);
    return v - v * frcp(e + 1.0f);                     // v*(1 - 1/(e^{2u}+1))
}

// ---------------- kernel 1: qkv GEMM + border zero + weight pack + bias pack -
// Sequential block ranges:
//   [0, 432)             qkv GEMM block: ALL 3 nc per block (LN1+A-stage once)
//   [432, 947)           zero PAD BORDER of kvp2 (disjoint from qkv writes)
//   [947, 992)           pack proj/fc1/fc2 weights -> wpack bf16 frag-linear
//   [992, 1208)          bias pack: F32, FULLY COALESCED layout
//                        [head*4+quart][c][qt 2][kt 4][tid 256][r 4] f32
#define QKVB 432
#define ZB   515     // ceil(21952*6/256)
#define WPB  45      // 5760 uint4 / 256 (rounded up)
#define BIASB 216    // 27 c x 4 quart x 2 qt
__global__ __launch_bounds__(256) void qkvz_kernel(
        const float* __restrict__ X, const float* __restrict__ W,
        const float* __restrict__ bias, const float* __restrict__ lnw,
        const float* __restrict__ lnb,
        const float* __restrict__ projw, const float* __restrict__ fc1w,
        const float* __restrict__ fc2w,
        const int* __restrict__ rpi, const float* __restrict__ rpb,
        unsigned short* __restrict__ q16, unsigned short* __restrict__ kvp2,
        uint4* __restrict__ wpack, float* __restrict__ biasF) {
    __shared__ uint4 Af4[2 * 3 * 4 * 16];   // 6 KB
    __shared__ uint4 Bf4[3 * 1152];         // 54 KB (all 3 nc)
    int bx = blockIdx.x, tid = threadIdx.x;

    if (bx >= QKVB + ZB + WPB) {   // ---- bias pack (f32, coalesced) ----
        int b2 = bx - (QKVB + ZB + WPB);   // 0..215
        int c  = b2 % 27;
        int qp = b2 / 27;                  // 0..7
        int quart = qp >> 1, qt = qp & 1;
        int quadp = (tid >> 4) & 3, m16p = tid & 15;
        int wavep = tid >> 6;
        int q = quart * 128 + wavep * 32 + qt * 16 + m16p;
        const int* rp = rpi + (long)q * NKEY + c * 64 + quadp * 8;
        #pragma unroll
        for (int kt = 0; kt < 4; ++kt) {
            // physical keys for S tile kt, quad quadp, r=0..3:
            //   c*64 + (kt>>1)*32 + (kt&1)*4 + quadp*8 + r
            int4 t = *(const int4*)(rp + (kt >> 1) * 32 + (kt & 1) * 4);
            const float* b0 = rpb + (long)t.x * 6;
            const float* b1 = rpb + (long)t.y * 6;
            const float* b2p = rpb + (long)t.z * 6;
            const float* b3 = rpb + (long)t.w * 6;
            float4 q0 = *(const float4*)b0; float2 r0 = *(const float2*)(b0 + 4);
            float4 q1 = *(const float4*)b1; float2 r1 = *(const float2*)(b1 + 4);
            float4 q2 = *(const float4*)b2p; float2 r2 = *(const float2*)(b2p + 4);
            float4 q3 = *(const float4*)b3; float2 r3 = *(const float2*)(b3 + 4);
            float4 h[6];
            h[0] = make_float4(q0.x * LOG2E, q1.x * LOG2E, q2.x * LOG2E, q3.x * LOG2E);
            h[1] = make_float4(q0.y * LOG2E, q1.y * LOG2E, q2.y * LOG2E, q3.y * LOG2E);
            h[2] = make_float4(q0.z * LOG2E, q1.z * LOG2E, q2.z * LOG2E, q3.z * LOG2E);
            h[3] = make_float4(q0.w * LOG2E, q1.w * LOG2E, q2.w * LOG2E, q3.w * LOG2E);
            h[4] = make_float4(r0.x * LOG2E, r1.x * LOG2E, r2.x * LOG2E, r3.x * LOG2E);
            h[5] = make_float4(r0.y * LOG2E, r1.y * LOG2E, r2.y * LOG2E, r3.y * LOG2E);
            #pragma unroll
            for (int head = 0; head < 6; ++head) {
                float* o = biasF + ((long)(head * 4 + quart) * 27 + c) * 8192
                           + (qt * 4 + kt) * 1024 + tid * 4;
                *(float4*)o = h[head];
            }
        }
        return;
    }
    if (bx >= QKVB + ZB) {   // ---- weight pack ----
        int u = (bx - QKVB - ZB) * 256 + tid;
        if (u < 5760) {
            int p = (u < 1152) ? u : (u < 3456 ? (u - 1152) % 1152 : (u - 3456) % 1152);
            int nn = p & 15, r = p >> 4, qg = r & 3, r2 = r >> 2;
            int kt = r2 % 3, ct = r2 / 3;
            int n = ct * 16 + nn, g = kt * 4 + qg;
            const float* src;
            if (u < 1152)      src = projw + n * 96 + g * 8;
            else if (u < 3456) { int nc = (u - 1152) / 1152; src = fc1w + (long)(nc * 96 + n) * 96 + g * 8; }
            else               { int kh = (u - 3456) / 1152; src = fc2w + (long)n * 192 + kh * 96 + g * 8; }
            const float4* s4 = (const float4*)src;
            float v[8];
            float4 t0 = s4[0], t1 = s4[1];
            v[0]=t0.x; v[1]=t0.y; v[2]=t0.z; v[3]=t0.w;
            v[4]=t1.x; v[5]=t1.y; v[6]=t1.z; v[7]=t1.w;
            wpack[u] = pack8(v);
        }
        return;
    }
    if (bx >= QKVB) {        // ---- pad-border zero ----
        int t = (bx - QKVB) * 256 + tid;
        if (t < 21952 * 6) {
            int head = t / PD3, pos = t % PD3;
            int d = pos / 784, h = (pos / 28) % 28, w = pos % 28;
            if (d < 2 || d >= 26 || h < 2 || h >= 26 || w < 2 || w >= 26) {
                uint4* p = (uint4*)(kvp2 + ((long)head * PD3 + pos) * 32);
                uint4 z = make_uint4(0, 0, 0, 0);
                p[0] = z; p[1] = z; p[2] = z; p[3] = z;
            }
        }
        return;
    }

    // ---- qkv GEMM block: 32 rows x all 288 output cols ----
    int row0 = bx * 32;

    if (tid < 128) {   // stage A with LN1: 32 rows, 4 threads/row (ONCE)
        int row = tid >> 2, part = tid & 3;
        int rt = row >> 4, mm = row & 15;
        float v[24];
        const float4* xp = (const float4*)(X + (long)(row0 + row) * 96 + part * 24);
        float s = 0.f, sq = 0.f;
        #pragma unroll
        for (int i = 0; i < 6; ++i) {
            float4 t = xp[i];
            v[i*4+0] = t.x; v[i*4+1] = t.y; v[i*4+2] = t.z; v[i*4+3] = t.w;
            s  += t.x + t.y + t.z + t.w;
            sq += t.x*t.x + t.y*t.y + t.z*t.z + t.w*t.w;
        }
        s  += __shfl_xor(s, 1);  s  += __shfl_xor(s, 2);
        sq += __shfl_xor(sq, 1); sq += __shfl_xor(sq, 2);
        float mean = s * (1.f / 96.f);
        float inv  = rsqrtf(sq * (1.f / 96.f) - mean * mean + 1e-5f);
        const float4* wp = (const float4*)(lnw + part * 24);
        const float4* bp = (const float4*)(lnb + part * 24);
        #pragma unroll
        for (int i = 0; i < 6; ++i) {
            float4 wv = wp[i], bv = bp[i];
            v[i*4+0] = (v[i*4+0] - mean) * inv * wv.x + bv.x;
            v[i*4+1] = (v[i*4+1] - mean) * inv * wv.y + bv.y;
            v[i*4+2] = (v[i*4+2] - mean) * inv * wv.z + bv.z;
            v[i*4+3] = (v[i*4+3] - mean) * inv * wv.w + bv.w;
        }
        #pragma unroll
        for (int gg = 0; gg < 3; ++gg) {
            int g = part * 3 + gg;
            int kt = g >> 2, qq = g & 3;
            Af4[((rt * 3 + kt) * 4 + qq) * 16 + mm] = pack8(v + gg * 8);
        }
    }
    for (int idx = tid; idx < 3 * 1152; idx += 256) {   // stage B: all 3 nc
        int nc = idx / 1152, p = idx % 1152;
        int n = p / 12;
        int g = p % 12;
        const float4* wp = (const float4*)(W + (long)(nc * 96 + n) * 96 + g * 8);
        float v[8];
        float4 t0 = wp[0], t1 = wp[1];
        v[0]=t0.x; v[1]=t0.y; v[2]=t0.z; v[3]=t0.w;
        v[4]=t1.x; v[5]=t1.y; v[6]=t1.z; v[7]=t1.w;
        int ct = n >> 4, nn = n & 15, kt = g >> 2, qg = g & 3;
        Bf4[nc * 1152 + ((ct * 3 + kt) * 4 + qg) * 16 + nn] = pack8(v);
    }
    __syncthreads();

    int wave = tid >> 6, lane = tid & 63;
    int qq = lane >> 4, mI = lane & 15;
    int rt = wave & 1, cg = wave >> 1;

    bf16x8 a[3];
    #pragma unroll
    for (int kt = 0; kt < 3; ++kt)
        a[kt] = *(const bf16x8*)&Af4[((rt * 3 + kt) * 4 + qq) * 16 + mI];

    #pragma unroll
    for (int nc = 0; nc < 3; ++nc) {
        f32x4 acc[3];
        #pragma unroll
        for (int j = 0; j < 3; ++j) acc[j] = (f32x4){0.f, 0.f, 0.f, 0.f};
        #pragma unroll
        for (int kt = 0; kt < 3; ++kt) {
            #pragma unroll
            for (int j = 0; j < 3; ++j) {
                bf16x8 b = *(const bf16x8*)&Bf4[nc * 1152 +
                               (((cg * 3 + j) * 3 + kt) * 4 + qq) * 16 + mI];
                acc[j] = __builtin_amdgcn_mfma_f32_16x16x32_bf16(a[kt], b, acc[j], 0, 0, 0);
            }
        }
        float bv[3];
        #pragma unroll
        for (int j = 0; j < 3; ++j) bv[j] = bias[nc * 96 + (cg * 3 + j) * 16 + mI];
        #pragma unroll
        for (int r = 0; r < 4; ++r) {
            int row = row0 + rt * 16 + qq * 4 + r;
            if (nc == 0) {
                unsigned short* op = q16 + (long)row * 96;
                // 0.25 (hd^-0.5) * log2(e): enables raw v_exp (2^x) in attention
                #pragma unroll
                for (int j = 0; j < 3; ++j)
                    op[(cg * 3 + j) * 16 + mI] = bfround(0.25f * LOG2E * (acc[j][r] + bv[j]));
            } else {
                int d = row / 576, hh = (row / 24) % 24, w2 = row % 24;
                long pos = ((long)(d + 2) * 28 + (hh + 2)) * 28 + (w2 + 2);
                #pragma unroll
                for (int j = 0; j < 3; ++j) {
                    int head = cg * 3 + j;
                    kvp2[((long)head * PD3 + pos) * 32 +
                         (nc == 2 ? 16 : 0) + mI] = bfround(acc[j][r] + bv[j]);
                }
            }
        }
    }
}

// ---------------- kernel 2: MFMA flash attention -----------------------------
// REVERTED to the R8 configuration -- the session's best-measured attn
// (43.3 us, VGPR 72). VKP=66 with plain scalar V-writes; the 1.12M LDS
// conflicts cost ~0.9 us chip-wide, while both attempted fixes (VKP=72 +
// write rotation, R10/R11) cost +15-20 us in scratch/VALU/registers.
// f32 bias from registers (C-input direct), depth-2 bias prefetch,
// sigma-permuted K (conflict-free kf reads), transposed V (2x ds_read_b128).
#define KSTR 20
#define VKP  66   // transposed-V row stride (shorts)

#define ATTN_STEP(P, BB)                                                      \
    {                                                                         \
        bool morekv = (cc + (P) + 1 < cn);                                    \
        if (morekv) stgn = *kvaddr(c0 + cc + (P) + 1);                        \
        __syncthreads();                                                      \
        bf16x4 kf[4];                                                         \
        _Pragma("unroll")                                                     \
        for (int kt = 0; kt < 4; ++kt)                                        \
            kf[kt] = *(const bf16x4*)&Ks[(P)][(kt * 16 + m16) * KSTR + quad * 4]; \
        bf16x8 vb0 = *(const bf16x8*)&Vt[(P)][m16 * VKP + quad * 8];          \
        bf16x8 vb1 = *(const bf16x8*)&Vt[(P)][m16 * VKP + 32 + quad * 8];     \
        f32x4 S[2][4];                                                        \
        _Pragma("unroll")                                                     \
        for (int qt = 0; qt < 2; ++qt) {                                      \
            _Pragma("unroll")                                                 \
            for (int kt = 0; kt < 4; ++kt)                                    \
                S[qt][kt] = mfma16(kf[kt], qf[qt], BB[qt][kt]);               \
        }                                                                     \
        if (cc + (P) + 2 < cn) {                                              \
            const float* bp = bbase + (long)(c0 + cc + (P) + 2) * 8192        \
                              + tid * 4;                                      \
            _Pragma("unroll")                                                 \
            for (int qt = 0; qt < 2; ++qt) {                                  \
                _Pragma("unroll")                                             \
                for (int kt = 0; kt < 4; ++kt)                                \
                    BB[qt][kt] = *(const f32x4*)(bp + (qt * 4 + kt) * 1024);  \
            }                                                                 \
        }                                                                     \
        bf16x8 P8[2][2];                                                      \
        _Pragma("unroll")                                                     \
        for (int qt = 0; qt < 2; ++qt) {                                      \
            _Pragma("unroll")                                                 \
            for (int u = 0; u < 2; ++u) {                                     \
                f32x4 p0, p1;                                                 \
                _Pragma("unroll")                                             \
                for (int r = 0; r < 4; ++r) {                                 \
                    p0[r] = fexp2(S[qt][2 * u][r]);                           \
                    p1[r] = fexp2(S[qt][2 * u + 1][r]);                       \
                }                                                             \
                union { struct { bf16x4 lo, hi; } h; bf16x8 v; } uu;          \
                uu.h.lo = pack4(p0); uu.h.hi = pack4(p1);                     \
                P8[qt][u] = uu.v;                                             \
                lacc[qt] = mfma32k(P8[qt][u], ones8, lacc[qt]);               \
            }                                                                 \
        }                                                                     \
        o[0] = mfma32k(P8[0][0], vb0, o[0]);                                  \
        o[1] = mfma32k(P8[1][0], vb0, o[1]);                                  \
        o[0] = mfma32k(P8[0][1], vb1, o[0]);                                  \
        o[1] = mfma32k(P8[1][1], vb1, o[1]);                                  \
        if (morekv) writeLDS((P) ^ 1, stgn);                                  \
    }

__global__ __launch_bounds__(256, 3) void attn_kernel(
        const unsigned short* __restrict__ q, const unsigned short* __restrict__ kvp2,
        const float* __restrict__ biasF, float* __restrict__ ao,
        float* __restrict__ lbuf) {
    __shared__ unsigned short Ks[2][64 * KSTR];   // 5120 B, sigma-permuted
    __shared__ unsigned short Vt[2][16 * VKP];    // 4224 B, transposed [dim][key]
    int bid = blockIdx.x;                 // 27*6*4*2 = 1296
    int w = bid / 48, rem = bid % 48;
    int head = rem >> 3;
    int quart = (rem >> 1) & 3, half = rem & 1;
    int wd8 = (w / 9) * 8, wh8 = ((w / 3) % 3) * 8, ww8 = (w % 3) * 8;
    int tid = threadIdx.x, wave = tid >> 6, lane = tid & 63;
    int quad = lane >> 4, m16 = lane & 15;
    int key = tid >> 2, part = tid & 3;
    int c0 = half ? 13 : 0;
    int cn = half ? 14 : 13;

    // sigma: key k = 32u+8b+4c+r  ->  LDS row 32u+16c+4b+r.  Makes the
    // interleaved kf read land on rows kt*16+m16 (linear, conflict-free).
    int skey = (key & 35) | ((key & 4) << 2) | ((key >> 1) & 12);

    auto kvaddr = [&](int c) -> const uint4* {
        int jg = c * 64 + key;
        int i = jg / 144, jh = (jg / 12) % 12, jw = jg % 12;
        long sp = ((long)(wd8 + i) * PDIM + (wh8 + jh)) * PDIM + (ww8 + jw);
        return (const uint4*)(kvp2 + ((long)head * PD3 + sp) * 32 + part * 8);
    };
    auto writeLDS = [&](int b, uint4 v) {
        if (part < 2) {
            *(uint2*)(&Ks[b][skey * KSTR + part * 8])     = make_uint2(v.x, v.y);
            *(uint2*)(&Ks[b][skey * KSTR + part * 8 + 4]) = make_uint2(v.z, v.w);
        } else {
            int d0 = (part - 2) * 8;
            unsigned short* vp = &Vt[b][d0 * VKP + key];
            vp[0 * VKP] = (unsigned short)(v.x);
            vp[1 * VKP] = (unsigned short)(v.x >> 16);
            vp[2 * VKP] = (unsigned short)(v.y);
            vp[3 * VKP] = (unsigned short)(v.y >> 16);
            vp[4 * VKP] = (unsigned short)(v.z);
            vp[5 * VKP] = (unsigned short)(v.z >> 16);
            vp[6 * VKP] = (unsigned short)(v.w);
            vp[7 * VKP] = (unsigned short)(v.w >> 16);
        }
    };

    bf16x4 qf[2];
    #pragma unroll
    for (int qt = 0; qt < 2; ++qt) {
        int ql = quart * 128 + wave * 32 + qt * 16 + m16;
        int ld = ql >> 6, lh = (ql >> 3) & 7, lw = ql & 7;
        int g = ((wd8 + ld) * 24 + (wh8 + lh)) * 24 + (ww8 + lw);
        qf[qt] = *(const bf16x4*)(q + (long)g * 96 + head * 16 + quad * 4);
    }

    // bias: [head*4+quart][c][qt][kt][tid][r] f32 -- coalesced float4 loads
    const float* bbase = biasF + ((long)(head * 4 + quart) * 27) * 8192;
    f32x4 bb0[2][4], bb1[2][4];
    {
        const float* bp = bbase + (long)c0 * 8192 + tid * 4;
        #pragma unroll
        for (int qt = 0; qt < 2; ++qt)
            #pragma unroll
            for (int kt = 0; kt < 4; ++kt)
                bb0[qt][kt] = *(const f32x4*)(bp + (qt * 4 + kt) * 1024);
        const float* bp1 = bbase + (long)(c0 + 1) * 8192 + tid * 4;
        #pragma unroll
        for (int qt = 0; qt < 2; ++qt)
            #pragma unroll
            for (int kt = 0; kt < 4; ++kt)
                bb1[qt][kt] = *(const f32x4*)(bp1 + (qt * 4 + kt) * 1024);
    }

    writeLDS(0, *kvaddr(c0));

    const bf16x8 ones8 = {(short)0x3F80, (short)0x3F80, (short)0x3F80, (short)0x3F80,
                          (short)0x3F80, (short)0x3F80, (short)0x3F80, (short)0x3F80};
    f32x4 o[2], lacc[2];
    o[0] = (f32x4){0.f,0.f,0.f,0.f}; o[1] = (f32x4){0.f,0.f,0.f,0.f};
    lacc[0] = o[0]; lacc[1] = o[1];
    uint4 stgn;

    for (int cc = 0; cc < cn; cc += 2) {
        ATTN_STEP(0, bb0)
        if (cc + 1 < cn) ATTN_STEP(1, bb1)
    }

    // epilogue: O in C layout [q=quad*4+r][dim=m16]
    float* aout = ao + (long)half * AOSTR;
    float* lout = lbuf + (long)half * LSTR;
    #pragma unroll
    for (int qt = 0; qt < 2; ++qt) {
        #pragma unroll
        for (int r = 0; r < 4; ++r) {
            int ql = quart * 128 + wave * 32 + qt * 16 + quad * 4 + r;
            int ld = ql >> 6, lh = (ql >> 3) & 7, lw = ql & 7;
            int g = ((wd8 + ld) * 24 + (wh8 + lh)) * 24 + (ww8 + lw);
            aout[(long)g * 96 + head * 16 + m16] = o[qt][r];
            if (m16 == 0) lout[g * 6 + head] = lacc[qt][r];
        }
    }
}

// ---------------- kernel 3: fused MLP, 512 thr x 64 rows, weights resident ---
// GELU via exp2-tanh form (7 VALU + 1 trans vs ~25 for erff; abs err ~1e-5,
// far below the bf16-quantization-dominated absmax).
#define X2S 100
__global__ __launch_bounds__(512) void mlp_kernel(
        const float* __restrict__ ao0, const float* __restrict__ ao1,
        const float* __restrict__ lbuf, const uint4* __restrict__ wpack,
        const float* __restrict__ projb, const float* __restrict__ x,
        const float* __restrict__ ln2w, const float* __restrict__ ln2b,
        const float* __restrict__ fc1b, const float* __restrict__ fc2b,
        float* __restrict__ out) {
    __shared__ uint4 Ws[5760];               // 92160 B: proj | fc1(2) | fc2(2)
    __shared__ uint4 Af4[4 * 3 * 4 * 16];    // 12288 B
    __shared__ float x2s[64 * X2S];          // 25600 B
    __shared__ unsigned short h16[64 * 192]; // 24576 B  => 154624 B total
    int tid = threadIdx.x;
    int row0 = blockIdx.x * 64;
    int wave = tid >> 6, lane = tid & 63;
    int qq = lane >> 4, mI = lane & 15;
    int rt = wave & 3, cg = wave >> 2;       // 4 row tiles x 2 col groups

    for (int idx = tid; idx < 5760; idx += 512) Ws[idx] = wpack[idx];

    if (tid < 256) {
        int row = tid >> 2, part = tid & 3;
        int rtA = row >> 4, mm = row & 15;
        int grow = row0 + row;
        const float4* a0 = (const float4*)(ao0 + (long)grow * 96 + part * 24);
        const float4* a1 = (const float4*)(ao1 + (long)grow * 96 + part * 24);
        int ha = (part * 3) >> 1, hb = ha + 1;
        float inva = 1.f / (lbuf[grow*6 + ha] + lbuf[LSTR + grow*6 + ha]);
        float invb = 1.f / (lbuf[grow*6 + hb] + lbuf[LSTR + grow*6 + hb]);
        float v[24];
        #pragma unroll
        for (int i = 0; i < 6; ++i) {
            float4 u0 = a0[i], u1 = a1[i];
            #pragma unroll
            for (int j = 0; j < 4; ++j) {
                int gc = part * 24 + i * 4 + j;
                float lv = ((gc >> 4) == ha) ? inva : invb;
                float s = (j==0?u0.x+u1.x : j==1?u0.y+u1.y : j==2?u0.z+u1.z : u0.w+u1.w);
                v[i*4+j] = s * lv;
            }
        }
        #pragma unroll
        for (int gg = 0; gg < 3; ++gg) {
            int g = part * 3 + gg;
            int kt = g >> 2, q4 = g & 3;
            Af4[((rtA * 3 + kt) * 4 + q4) * 16 + mm] = pack8(v + gg * 8);
        }
    }
    __syncthreads();

    {
        f32x4 acc[3];
        #pragma unroll
        for (int j = 0; j < 3; ++j) acc[j] = (f32x4){0.f,0.f,0.f,0.f};
        #pragma unroll
        for (int kt = 0; kt < 3; ++kt) {
            bf16x8 a = *(const bf16x8*)&Af4[((rt * 3 + kt) * 4 + qq) * 16 + mI];
            #pragma unroll
            for (int j = 0; j < 3; ++j) {
                bf16x8 b = *(const bf16x8*)&Ws[(((cg * 3 + j) * 3 + kt) * 4 + qq) * 16 + mI];
                acc[j] = __builtin_amdgcn_mfma_f32_16x16x32_bf16(a, b, acc[j], 0, 0, 0);
            }
        }
        float bv[3];
        #pragma unroll
        for (int j = 0; j < 3; ++j) bv[j] = projb[(cg * 3 + j) * 16 + mI];
        #pragma unroll
        for (int r = 0; r < 4; ++r) {
            int row = rt * 16 + qq * 4 + r;
            int grow = row0 + row;
            #pragma unroll
            for (int j = 0; j < 3; ++j) {
                int col = (cg * 3 + j) * 16 + mI;
                x2s[row * X2S + col] = acc[j][r] + bv[j] + x[(long)grow * 96 + col];
            }
        }
    }
    __syncthreads();

    if (tid < 256) {
        int row = tid >> 2, part = tid & 3;
        int rtA = row >> 4, mm = row & 15;
        float v[24];
        const float4* xp = (const float4*)(x2s + row * X2S + part * 24);
        float s = 0.f, sq = 0.f;
        #pragma unroll
        for (int i = 0; i < 6; ++i) {
            float4 t = xp[i];
            v[i*4+0] = t.x; v[i*4+1] = t.y; v[i*4+2] = t.z; v[i*4+3] = t.w;
            s  += t.x + t.y + t.z + t.w;
            sq += t.x*t.x + t.y*t.y + t.z*t.z + t.w*t.w;
        }
        s  += __shfl_xor(s, 1);  s  += __shfl_xor(s, 2);
        sq += __shfl_xor(sq, 1); sq += __shfl_xor(sq, 2);
        float mean = s * (1.f / 96.f);
        float inv  = rsqrtf(sq * (1.f / 96.f) - mean * mean + 1e-5f);
        const float4* wp = (const float4*)(ln2w + part * 24);
        const float4* bp = (const float4*)(ln2b + part * 24);
        #pragma unroll
        for (int i = 0; i < 6; ++i) {
            float4 wv = wp[i], bv = bp[i];
            v[i*4+0] = (v[i*4+0] - mean) * inv * wv.x + bv.x;
            v[i*4+1] = (v[i*4+1] - mean) * inv * wv.y + bv.y;
            v[i*4+2] = (v[i*4+2] - mean) * inv * wv.z + bv.z;
            v[i*4+3] = (v[i*4+3] - mean) * inv * wv.w + bv.w;
        }
        #pragma unroll
        for (int gg = 0; gg < 3; ++gg) {
            int g = part * 3 + gg;
            int kt = g >> 2, q4 = g & 3;
            Af4[((rtA * 3 + kt) * 4 + q4) * 16 + mm] = pack8(v + gg * 8);
        }
    }
    __syncthreads();

    #pragma unroll
    for (int nc = 0; nc < 2; ++nc) {
        f32x4 acc[3];
        #pragma unroll
        for (int j = 0; j < 3; ++j) acc[j] = (f32x4){0.f,0.f,0.f,0.f};
        #pragma unroll
        for (int kt = 0; kt < 3; ++kt) {
            bf16x8 a = *(const bf16x8*)&Af4[((rt * 3 + kt) * 4 + qq) * 16 + mI];
            #pragma unroll
            for (int j = 0; j < 3; ++j) {
                bf16x8 b = *(const bf16x8*)&Ws[1152 + nc * 1152 +
                               (((cg * 3 + j) * 3 + kt) * 4 + qq) * 16 + mI];
                acc[j] = __builtin_amdgcn_mfma_f32_16x16x32_bf16(a, b, acc[j], 0, 0, 0);
            }
        }
        float bv[3];
        #pragma unroll
        for (int j = 0; j < 3; ++j) bv[j] = fc1b[nc * 96 + (cg * 3 + j) * 16 + mI];
        #pragma unroll
        for (int r = 0; r < 4; ++r) {
            int row = rt * 16 + qq * 4 + r;
            #pragma unroll
            for (int j = 0; j < 3; ++j) {
                int col = nc * 96 + (cg * 3 + j) * 16 + mI;
                float v = acc[j][r] + bv[j];
                float g = fgelu(v);
                int fi = (((row >> 4) * 6 + (col >> 5)) * 4 + ((col >> 3) & 3)) * 16 + (row & 15);
                h16[fi * 8 + (col & 7)] = bfround(g);
            }
        }
    }
    __syncthreads();

    f32x4 acc2[3];
    #pragma unroll
    for (int j = 0; j < 3; ++j) acc2[j] = (f32x4){0.f,0.f,0.f,0.f};
    #pragma unroll
    for (int kh = 0; kh < 2; ++kh) {
        #pragma unroll
        for (int kt = 0; kt < 3; ++kt) {
            int ktA = kh * 3 + kt;
            bf16x8 a = *(const bf16x8*)&h16[(((rt * 6 + ktA) * 4 + qq) * 16 + mI) * 8];
            #pragma unroll
            for (int j = 0; j < 3; ++j) {
                bf16x8 b = *(const bf16x8*)&Ws[3456 + kh * 1152 +
                               (((cg * 3 + j) * 3 + kt) * 4 + qq) * 16 + mI];
                acc2[j] = __builtin_amdgcn_mfma_f32_16x16x32_bf16(a, b, acc2[j], 0, 0, 0);
            }
        }
    }
    float bv[3];
    #pragma unroll
    for (int j = 0; j < 3; ++j) bv[j] = fc2b[(cg * 3 + j) * 16 + mI];
    #pragma unroll
    for (int r = 0; r < 4; ++r) {
        int row = rt * 16 + qq * 4 + r;
        int grow = row0 + row;
        #pragma unroll
        for (int j = 0; j < 3; ++j) {
            int col = (cg * 3 + j) * 16 + mI;
            out[(long)grow * 96 + col] = acc2[j][r] + bv[j] + x2s[row * X2S + col];
        }
    }
}

// ---------------- launcher ---------------------------------------------------
extern "C" void kernel_launch(void* const* d_in, const int* in_sizes, int n_in,
                              void* d_out, int out_size, void* d_ws, size_t ws_size,
                              hipStream_t stream) {
    const float* x     = (const float*)d_in[0];
    const float* ln1w  = (const float*)d_in[1];
    const float* ln1b  = (const float*)d_in[2];
    const float* qkvw  = (const float*)d_in[3];
    const float* qkvb  = (const float*)d_in[4];
    const float* rpb   = (const float*)d_in[5];
    const float* projw = (const float*)d_in[6];
    const float* projb = (const float*)d_in[7];
    const float* ln2w  = (const float*)d_in[8];
    const float* ln2b  = (const float*)d_in[9];
    const float* fc1w  = (const float*)d_in[10];
    const float* fc1b  = (const float*)d_in[11];
    const float* fc2w  = (const float*)d_in[12];
    const float* fc2b  = (const float*)d_in[13];
    const int*   rpi   = (const int*)d_in[14];
    float* outp = (float*)d_out;

    float* ws = (float*)d_ws;
    float*          aop    = ws;                               // 2 x 1,327,104 f
    unsigned short* q16    = (unsigned short*)(ws + 2654208);  // 663,552 f
    unsigned short* kvp16  = (unsigned short*)(ws + 3317760);  // 2,107,392 f
    float*          biasF  = ws + 5425152;                     // 5,308,416 f (f32)
    float*          lbuf   = ws + 10733568;                    // 165,888 f
    uint4*          wpack  = (uint4*)(ws + 10899456);          // 23,040 f (5760 u4)

    qkvz_kernel<<<QKVB + ZB + WPB + BIASB, 256, 0, stream>>>(
        x, qkvw, qkvb, ln1w, ln1b, projw, fc1w, fc2w, rpi, rpb,
        q16, kvp16, wpack, biasF);
    attn_kernel<<<NWIN * NHEADS * 4 * 2, 256, 0, stream>>>(q16, kvp16, biasF, aop, lbuf);
    mlp_kernel<<<LTOK / 64, 512, 0, stream>>>(aop, aop + AOSTR, lbuf, wpack, projb, x,
                                              ln2w, ln2b, fc1b, fc2b, outp);
}